// Round 10
// baseline (238.702 us; speedup 1.0000x reference)
//
#include <hip/hip_runtime.h>

// out[b,h,w,u] = sum_d (w[u,d] - x[b,h,w,d])^2 = ||x||^2 - 2 x.w + ||w||^2
// x: [524288, 64] fp32 (134 MB read once), w: [64,64] fp32 (16 KB),
// out: [524288, 64] fp32 (134 MB written once). Memory-bound.
//
// Ladder:
// R1: spills proved memory moves more bytes given more requests.
// R2: wave count not the lever (2x waves -> +-0; pins ~2.45 TB/s useful).
// R3: +1 in-flight tile -> +9% BW. Per-wave MLP is the one positive lever.
// R4: compiler sinks register pipelines (VGPR 60 proved it).
// R5: LDS-DMA "pipeline" measured exactly serial (82us). Post-R9 analysis:
//     it NEVER pipelined: (a) LLVM's waitcnt pass inserts a conservative
//     vmcnt(0) between global_load_lds and any compiler-visible ds_read of
//     LDS (all LDS-DMA shares one scoreboard slot), overriding my counted
//     vmcnt(12); (b) loads-only-safe counting with stores interleaved in the
//     queue over-retires the prefetch DMAs (the 12 youngest entries are
//     mostly stores) -> effective depth ~1.
// R6: builtin nontemporal store does not change MALL behavior (FETCH
//     identical). LDS bounce write had 2x bank imbalance.
// R7-R9: asm-store + LDS-bounce epilogue failed 3x with byte-identical
//     absmax (deterministic, sync-invariant) -> abandoned that epilogue line.
// R10: test the MLP lever FOR REAL, everything else reverted to passing form:
//     (a) slot reads via inline-asm ds_read_b128 (invisible to the waitcnt
//         pass -> no auto-vmcnt(0)), + lgkmcnt(0) + sched_barrier (rule #18);
//     (b) restage at TOP of iteration (tile k+3 into the slot read last
//         iteration) so the loads-only wait vmcnt(12) forces only tile k's
//         DMA and keeps 3 tiles (12 KB/wave) truly in flight. OOO-store-safe:
//         if L(k) outstanding, >=16 loads outstanding -> count<=12 unreachable.
//     (c) stores: plain per-lane dwordx4 from acc (compiler-visible, R5 form).

typedef float  float4v  __attribute__((ext_vector_type(4)));
typedef __bf16 bf16x8   __attribute__((ext_vector_type(8)));

static constexpr int kRows  = 16 * 128 * 256;   // 524288
static constexpr int kTiles = kRows / 16;       // 32768
static constexpr int kWaves = 1024 * 4;         // grid fixed: 1024 blocks x 4 waves
static constexpr int kIters = kTiles / kWaves;  // 8, exact
static constexpr int kSlots = 4;                // LDS slots/wave

typedef const __attribute__((address_space(1))) void gas_t;  // global
typedef __attribute__((address_space(3))) void las_t;        // LDS

__device__ __forceinline__ bf16x8 cvt2(float4v a, float4v b) {
  bf16x8 r;
  r[0] = (__bf16)a[0]; r[1] = (__bf16)a[1]; r[2] = (__bf16)a[2]; r[3] = (__bf16)a[3];
  r[4] = (__bf16)b[0]; r[5] = (__bf16)b[1]; r[6] = (__bf16)b[2]; r[7] = (__bf16)b[3];
  return r;
}

__global__ __launch_bounds__(256) void sqdist_kernel(
    const float* __restrict__ X, const float* __restrict__ W,
    float* __restrict__ Out) {
  // 4 waves x 4 slots x 256 granules(16B) = 64 KB -> 2 blocks/CU resident.
  __shared__ float4v lds[4][kSlots][256];

  const int lane = threadIdx.x & 63;
  const int wid  = threadIdx.x >> 6;
  const int q    = lane >> 4;   // quad 0..3
  const int m    = lane & 15;

  // ---- Setup: w fragments (A operand) + redistributed ||w||^2 ----
  bf16x8 aw[4][2];
  float  w2adj[4][4];  // [ut][reg]: ||w_u||^2 for u = 16*ut + q*4 + reg
#pragma unroll
  for (int ut = 0; ut < 4; ++ut) {
    const float4v* wr = (const float4v*)(W + (ut * 16 + m) * 64);
    float4v v0 = wr[q * 2];
    float4v v1 = wr[q * 2 + 1];
    float4v v2 = wr[8 + q * 2];
    float4v v3 = wr[8 + q * 2 + 1];
    aw[ut][0] = cvt2(v0, v1);
    aw[ut][1] = cvt2(v2, v3);
    float s = 0.f;
#pragma unroll
    for (int i = 0; i < 4; ++i)
      s += v0[i] * v0[i] + v1[i] * v1[i] + v2[i] * v2[i] + v3[i] * v3[i];
    s += __shfl_xor(s, 16);
    s += __shfl_xor(s, 32);
#pragma unroll
    for (int r = 0; r < 4; ++r)
      w2adj[ut][r] = __shfl(s, q * 4 + r);
  }

  const int gw = blockIdx.x * 4 + wid;  // wave id 0..4095; 8 tiles/wave

  // ---- Staging source offsets (floats within a 1024-float tile) ----
  // Staging inst c, lane l writes LDS granule c*64+l = physical (row r=c*4+q,
  // granule j=m). Physical (r,j) holds logical granule (r, j^(r&7)) -> XOR on
  // the GLOBAL source (rule #21), stays within the 256B row -> coalescing kept.
  int soff[4];
#pragma unroll
  for (int c = 0; c < 4; ++c) {
    const int r = c * 4 + q;
    soff[c] = r * 64 + ((m ^ (r & 7)) << 2);
  }

  // ---- Prologue: stage tiles 0..3 into slots 0..3 (16 DMA loads) ----
#pragma unroll
  for (int p = 0; p < kSlots; ++p) {
    const float* src = X + (size_t)(gw + p * kWaves) * 1024;
#pragma unroll
    for (int c = 0; c < 4; ++c) {
      __builtin_amdgcn_global_load_lds((gas_t*)(src + soff[c]),
                                       (las_t*)&lds[wid][p][c * 64], 16, 0, 0);
    }
  }

  // Fragment read granules: lane (q,m) needs logical granules {2q,2q+1,
  // 8+2q,8+2q+1} of row m -> physical ^ (m&7) (bit3 untouched).
  const int gA = (2 * q)     ^ (m & 7);
  const int gB = (2 * q + 1) ^ (m & 7);

#pragma unroll
  for (int k = 0; k < kIters; ++k) {
    // ---- Restage FIRST (tile k+3 into the slot read during iter k-1).
    // Putting the loads at the top keeps the queue loads-dense, so the
    // loads-only wait below does not force prefetches to retire.
    if (k >= 1 && k + 3 < kIters) {  // k = 1..4 -> tiles 4..7
      const float* src = X + (size_t)(gw + (k + 3) * kWaves) * 1024;
#pragma unroll
      for (int c = 0; c < 4; ++c) {
        __builtin_amdgcn_global_load_lds(
            (gas_t*)(src + soff[c]),
            (las_t*)&lds[wid][(k + 3) & (kSlots - 1)][c * 64], 16, 0, 0);
      }
    }

    // ---- Wait for tile k's 4 DMA loads. N = number of younger LOADS only
    // (OOO-store-safe: loads retire in order among themselves; if L(k) were
    // outstanding, >= 16 loads would be outstanding and count<=12 could not
    // be reached). Steady state k=0..4: L(k+1),L(k+2),L(k+3) = 12.
    if (k <= 4)      asm volatile("s_waitcnt vmcnt(12)" ::: "memory");
    else if (k == 5) asm volatile("s_waitcnt vmcnt(8)"  ::: "memory");
    else if (k == 6) asm volatile("s_waitcnt vmcnt(4)"  ::: "memory");
    else             asm volatile("s_waitcnt vmcnt(0)"  ::: "memory");
    __builtin_amdgcn_sched_barrier(0);

    // ---- Slot reads via INLINE ASM ds_read_b128: invisible to the waitcnt
    // pass, so it cannot insert its conservative LDS-DMA vmcnt(0) here.
    // Ordering: volatile asms keep program order; lgkmcnt(0)+sched_barrier(0)
    // (rule #18) pins the uses below the data arrival.
    float4v* slot = lds[wid][k & (kSlots - 1)];
    const unsigned a0 = (unsigned)(size_t)(las_t*)&slot[m * 16 + gA];
    const unsigned a1 = (unsigned)(size_t)(las_t*)&slot[m * 16 + gB];
    const unsigned a2 = (unsigned)(size_t)(las_t*)&slot[m * 16 + 8 + gA];
    const unsigned a3 = (unsigned)(size_t)(las_t*)&slot[m * 16 + 8 + gB];
    float4v x0, x1, x2, x3;
    asm volatile("ds_read_b128 %0, %1" : "=v"(x0) : "v"(a0));
    asm volatile("ds_read_b128 %0, %1" : "=v"(x1) : "v"(a1));
    asm volatile("ds_read_b128 %0, %1" : "=v"(x2) : "v"(a2));
    asm volatile("ds_read_b128 %0, %1" : "=v"(x3) : "v"(a3));
    asm volatile("s_waitcnt lgkmcnt(0)" ::: "memory");
    __builtin_amdgcn_sched_barrier(0);

    // ||x_row||^2 in fp32 (partial over this lane's 16 elems, reduce quads)
    float s = 0.f;
#pragma unroll
    for (int i = 0; i < 4; ++i)
      s += x0[i] * x0[i] + x1[i] * x1[i] + x2[i] * x2[i] + x3[i] * x3[i];
    s += __shfl_xor(s, 16);
    s += __shfl_xor(s, 32);      // s = ||x_(tile*16+m)||^2 (C-col of lane = m)

    bf16x8 bx0 = cvt2(x0, x1);
    bf16x8 bx1 = cvt2(x2, x3);

    // 8 MFMAs: acc[ut][reg] = dot(w[16*ut + q*4 + reg], x[tile*16 + m])
    float4v acc[4];
#pragma unroll
    for (int ut = 0; ut < 4; ++ut) {
      float4v z = {0.f, 0.f, 0.f, 0.f};
      acc[ut] = __builtin_amdgcn_mfma_f32_16x16x32_bf16(aw[ut][0], bx0, z, 0, 0, 0);
      acc[ut] = __builtin_amdgcn_mfma_f32_16x16x32_bf16(aw[ut][1], bx1, acc[ut], 0, 0, 0);
    }

    // Epilogue: out = x2 + w2 - 2*dot ; 4x dwordx4 coalesced stores (plain,
    // compiler-visible -> auto-waited, endpgm-safe).
    const int tile = gw + k * kWaves;
    float4v* orow = (float4v*)(Out + (size_t)(tile * 16 + m) * 64);
#pragma unroll
    for (int ut = 0; ut < 4; ++ut) {
      float4v o;
#pragma unroll
      for (int r = 0; r < 4; ++r)
        o[r] = fmaf(-2.f, acc[ut][r], s + w2adj[ut][r]);
      orow[ut * 4 + q] = o;   // floats [16*ut + 4*q .. +3] of this row
    }
  }
}

extern "C" void kernel_launch(void* const* d_in, const int* in_sizes, int n_in,
                              void* d_out, int out_size, void* d_ws, size_t ws_size,
                              hipStream_t stream) {
  const float* X = (const float*)d_in[0];
  const float* W = (const float*)d_in[1];
  float* Out = (float*)d_out;
  // 1024 blocks x 256 (4 waves): 8 tiles/wave exact; 64KB LDS -> 2 blocks/CU.
  // 4-slot DMA pipeline with asm ds_reads (no compiler auto-drain) and
  // restage-at-top so counted vmcnt keeps 3 tiles (12KB/wave) in flight.
  sqdist_kernel<<<1024, 256, 0, stream>>>(X, W, Out);
}

// Round 11
// 234.777 us; speedup vs baseline: 1.0167x; 1.0167x over previous
//
#include <hip/hip_runtime.h>

// out[b,h,w,u] = sum_d (w[u,d] - x[b,h,w,d])^2 = ||x||^2 - 2 x.w + ||w||^2
// x: [524288, 64] fp32 (134 MB read once), w: [64,64] fp32 (16 KB),
// out: [524288, 64] fp32 (134 MB written once). Memory-bound.
//
// Ladder:
// R1: spills proved memory moves more bytes given more requests.
// R2: wave count not the lever (2x waves -> +-0).
// R3: +1 in-flight tile -> +9% BW. Per-wave MLP: the one positive signal.
// R4: compiler sinks source-level register pipelines (VGPR 60 proved it).
// R5/R10: LDS-DMA pipelines land serial (~84us). R10 left one compiler
//     serialization point: restage global_load_lds is compiler-visible, and
//     LLVM's LDS-DMA WAW tracking can insert its own vmcnt(0) before the
//     restage -> ambiguous experiment.
// R6: builtin nontemporal store does not change MALL behavior.
// R7-R9: sc0/sc1/nt no-allocate stores under a harness that MEMSETS Out
//     through the cached path = dirty zero lines overlay HBM data on flush.
//     Byte-identical deterministic failures. Per-inst output MALL-bypass is
//     incompatible with this harness. Also: the harness's 537MB inter-
//     iteration fill evicts X from MALL regardless -> FETCH=65.7MB is
//     harness-imposed, not store-policy-imposed.
// R11: the UNAMBIGUOUS MLP test. Register pipeline, depth 3, via inline-asm
//     global_load_dwordx4 (compiler never sees the loads -> cannot sink,
//     cannot insert waits). Named slots A/B/C, hand-unrolled 8 iterations,
//     all indices static. The s_waitcnt vmcnt(N) asm carries the slot's 4
//     registers as "+v" tied operands so all consumption data-depends on the
//     wait. Loads-only counts {8,8,8,8,8,8,4,0} are OOO-store-safe. No LDS.
//     Flat result here = per-wave MLP definitively dead = structural floor.

typedef float  float4v  __attribute__((ext_vector_type(4)));
typedef __bf16 bf16x8   __attribute__((ext_vector_type(8)));

static constexpr int kRows  = 16 * 128 * 256;   // 524288
static constexpr int kTiles = kRows / 16;       // 32768
static constexpr int kWaves = 1024 * 4;         // grid fixed: 1024 blocks x 4 waves
static constexpr int kIters = kTiles / kWaves;  // 8, exact

__device__ __forceinline__ bf16x8 cvt2(float4v a, float4v b) {
  bf16x8 r;
  r[0] = (__bf16)a[0]; r[1] = (__bf16)a[1]; r[2] = (__bf16)a[2]; r[3] = (__bf16)a[3];
  r[4] = (__bf16)b[0]; r[5] = (__bf16)b[1]; r[6] = (__bf16)b[2]; r[7] = (__bf16)b[3];
  return r;
}

// Issue tile t's 4 lane-fragment loads into a named register slot.
// Lane (q,m) of the wave reads row (t*16+m), floats [8q..8q+7] and
// [32+8q..32+8q+7] as 4 dwordx4. Early-clobber keeps dests disjoint from
// the address operands. Volatile asm: cannot be sunk or reordered.
#define ISSUE(s0v, s1v, s2v, s3v, t)                                          \
  do {                                                                        \
    const float* p_ = X + (size_t)((t) * 16 + m) * 64 + q * 8;                \
    asm volatile("global_load_dwordx4 %0, %4, off\n\t"                        \
                 "global_load_dwordx4 %1, %5, off\n\t"                        \
                 "global_load_dwordx4 %2, %6, off\n\t"                        \
                 "global_load_dwordx4 %3, %7, off"                            \
                 : "=&v"(s0v), "=&v"(s1v), "=&v"(s2v), "=&v"(s3v)             \
                 : "v"(p_), "v"(p_ + 4), "v"(p_ + 32), "v"(p_ + 36));         \
  } while (0)

// Wait until tile's loads returned. N = count of YOUNGER LOADS only
// (loads retire in order among themselves; interleaved stores only make the
// wait stricter -> safe under out-of-order store retirement). The "+v" ties
// make every later use of the slot data-depend on this wait.
#define WAITC(Nstr, s0v, s1v, s2v, s3v)                                       \
  asm volatile("s_waitcnt vmcnt(" Nstr ")"                                    \
               : "+v"(s0v), "+v"(s1v), "+v"(s2v), "+v"(s3v)::"memory")

__global__ __launch_bounds__(256) void sqdist_kernel(
    const float* __restrict__ X, const float* __restrict__ W,
    float* __restrict__ Out) {
  const int lane = threadIdx.x & 63;
  const int wid  = threadIdx.x >> 6;
  const int q    = lane >> 4;   // quad 0..3
  const int m    = lane & 15;

  // ---- Setup: w fragments (A operand) + redistributed ||w||^2 ----
  bf16x8 aw[4][2];
  float  w2adj[4][4];  // [ut][reg]: ||w_u||^2 for u = 16*ut + q*4 + reg
#pragma unroll
  for (int ut = 0; ut < 4; ++ut) {
    const float4v* wr = (const float4v*)(W + (ut * 16 + m) * 64);
    float4v v0 = wr[q * 2];
    float4v v1 = wr[q * 2 + 1];
    float4v v2 = wr[8 + q * 2];
    float4v v3 = wr[8 + q * 2 + 1];
    aw[ut][0] = cvt2(v0, v1);
    aw[ut][1] = cvt2(v2, v3);
    float s = 0.f;
#pragma unroll
    for (int i = 0; i < 4; ++i)
      s += v0[i] * v0[i] + v1[i] * v1[i] + v2[i] * v2[i] + v3[i] * v3[i];
    s += __shfl_xor(s, 16);
    s += __shfl_xor(s, 32);
#pragma unroll
    for (int r = 0; r < 4; ++r)
      w2adj[ut][r] = __shfl(s, q * 4 + r);
  }

  const int gw = blockIdx.x * 4 + wid;  // wave id 0..4095; 8 tiles/wave

  // Consume one tile held in registers: norm, cvt, 8 MFMAs, plain stores
  // (compiler-visible stores -> auto-waited, endpgm-safe; R0-R6/R10 form).
  auto consume = [&](float4v x0, float4v x1, float4v x2, float4v x3, int t) {
    float s = 0.f;
#pragma unroll
    for (int i = 0; i < 4; ++i)
      s += x0[i] * x0[i] + x1[i] * x1[i] + x2[i] * x2[i] + x3[i] * x3[i];
    s += __shfl_xor(s, 16);
    s += __shfl_xor(s, 32);      // s = ||x_(t*16+m)||^2 (C-col of lane = m)

    bf16x8 bx0 = cvt2(x0, x1);
    bf16x8 bx1 = cvt2(x2, x3);

    float4v acc[4];
#pragma unroll
    for (int ut = 0; ut < 4; ++ut) {
      float4v z = {0.f, 0.f, 0.f, 0.f};
      acc[ut] = __builtin_amdgcn_mfma_f32_16x16x32_bf16(aw[ut][0], bx0, z, 0, 0, 0);
      acc[ut] = __builtin_amdgcn_mfma_f32_16x16x32_bf16(aw[ut][1], bx1, acc[ut], 0, 0, 0);
    }

    float4v* orow = (float4v*)(Out + (size_t)(t * 16 + m) * 64);
#pragma unroll
    for (int ut = 0; ut < 4; ++ut) {
      float4v o;
#pragma unroll
      for (int r = 0; r < 4; ++r)
        o[r] = fmaf(-2.f, acc[ut][r], s + w2adj[ut][r]);
      orow[ut * 4 + q] = o;   // floats [16*ut + 4*q .. +3] of this row
    }
  };

  // ---- Depth-3 register pipeline over exactly 8 tiles, hand-unrolled ----
  float4v A0, A1, A2, A3, B0, B1, B2, B3, C0, C1, C2, C3;

  ISSUE(A0, A1, A2, A3, gw + 0 * kWaves);
  ISSUE(B0, B1, B2, B3, gw + 1 * kWaves);
  ISSUE(C0, C1, C2, C3, gw + 2 * kWaves);

  WAITC("8", A0, A1, A2, A3);  consume(A0, A1, A2, A3, gw + 0 * kWaves);
  ISSUE(A0, A1, A2, A3, gw + 3 * kWaves);

  WAITC("8", B0, B1, B2, B3);  consume(B0, B1, B2, B3, gw + 1 * kWaves);
  ISSUE(B0, B1, B2, B3, gw + 4 * kWaves);

  WAITC("8", C0, C1, C2, C3);  consume(C0, C1, C2, C3, gw + 2 * kWaves);
  ISSUE(C0, C1, C2, C3, gw + 5 * kWaves);

  WAITC("8", A0, A1, A2, A3);  consume(A0, A1, A2, A3, gw + 3 * kWaves);
  ISSUE(A0, A1, A2, A3, gw + 6 * kWaves);

  WAITC("8", B0, B1, B2, B3);  consume(B0, B1, B2, B3, gw + 4 * kWaves);
  ISSUE(B0, B1, B2, B3, gw + 7 * kWaves);

  WAITC("8", C0, C1, C2, C3);  consume(C0, C1, C2, C3, gw + 5 * kWaves);

  WAITC("4", A0, A1, A2, A3);  consume(A0, A1, A2, A3, gw + 6 * kWaves);

  WAITC("0", B0, B1, B2, B3);  consume(B0, B1, B2, B3, gw + 7 * kWaves);
}

extern "C" void kernel_launch(void* const* d_in, const int* in_sizes, int n_in,
                              void* d_out, int out_size, void* d_ws, size_t ws_size,
                              hipStream_t stream) {
  const float* X = (const float*)d_in[0];
  const float* W = (const float*)d_in[1];
  float* Out = (float*)d_out;
  // 1024 blocks x 256 (4 waves) = 4096 waves; 8 tiles/wave, depth-3 asm
  // register pipeline: 8 KB of reads provably in flight per wave steady-state.
  sqdist_kernel<<<1024, 256, 0, stream>>>(X, W, Out);
}

// Round 12
// 233.561 us; speedup vs baseline: 1.0220x; 1.0052x over previous
//
#include <hip/hip_runtime.h>

// out[b,h,w,u] = sum_d (w[u,d] - x[b,h,w,d])^2 = ||x||^2 - 2 x.w + ||w||^2
// x: [524288, 64] fp32 (134 MB read once), w: [64,64] fp32 (16 KB),
// out: [524288, 64] fp32 (134 MB written once). Memory-bound.
//
// Ladder:
// R1: spill traffic flows at 5.3 TB/s MARGINAL -> pipes have headroom.
// R2: wave count null. R3: +1 tile in flight +9%. R4: compiler sinks reg
//     pipelines. R5/R10: LDS-DMA pipelines serial-or-null (~84us).
// R6: full-line stores null; builtin-nt does not control MALL.
// R7-R9: no-allocate stores incompatible with harness (cached-path memset
//     overlays HBM data). FETCH=65.7MB is cross-dispatch MALL residual.
// R11: UNAMBIGUOUS reg pipeline (asm loads, tied-operand waits, depth 3,
//     8KB+/wave provably in flight) -> STILL 81.6us. Eight structurally
//     distinct kernels all land at 82+-3us with nothing busy (VALU 5%,
//     MFMA 2%, HBM 30%). Writes proven free (harness fill: 6.5 TB/s at 9%
//     occupancy). Back-out: 134MB reads / 81.5us = 1.65 TB/s effective read
//     rate == the whole dispatch time. The read DEMAND path is serialized
//     at a per-CU queue depth no software lever has touched. Suspect: the
//     vector L1 (every read so far allocated through it; L1 is pure
//     overhead for a read-once stream).
// R12: R11 + sc0 on the asm loads (one-token A/B). glc/sc0 loads bypass the
//     per-CU L1 -> requests go straight to the XCD L2's deeper queue. MALL
//     allocation unchanged (sc0 != nt, cross-dispatch hits preserved).
//     Helps -> L1 was the serializer, iterate. Flat -> every catalog lever
//     measured null; declare roofline.

typedef float  float4v  __attribute__((ext_vector_type(4)));
typedef __bf16 bf16x8   __attribute__((ext_vector_type(8)));

static constexpr int kRows  = 16 * 128 * 256;   // 524288
static constexpr int kTiles = kRows / 16;       // 32768
static constexpr int kWaves = 1024 * 4;         // grid fixed: 1024 blocks x 4 waves
static constexpr int kIters = kTiles / kWaves;  // 8, exact

__device__ __forceinline__ bf16x8 cvt2(float4v a, float4v b) {
  bf16x8 r;
  r[0] = (__bf16)a[0]; r[1] = (__bf16)a[1]; r[2] = (__bf16)a[2]; r[3] = (__bf16)a[3];
  r[4] = (__bf16)b[0]; r[5] = (__bf16)b[1]; r[6] = (__bf16)b[2]; r[7] = (__bf16)b[3];
  return r;
}

// Issue tile t's 4 lane-fragment loads into a named register slot, L1-BYPASS
// (sc0). Lane (q,m) reads row (t*16+m), floats [8q..8q+7], [32+8q..32+8q+7].
// Volatile asm: cannot be sunk or reordered; early-clobber keeps dests
// disjoint from address operands.
#define ISSUE(s0v, s1v, s2v, s3v, t)                                          \
  do {                                                                        \
    const float* p_ = X + (size_t)((t) * 16 + m) * 64 + q * 8;                \
    asm volatile("global_load_dwordx4 %0, %4, off sc0\n\t"                    \
                 "global_load_dwordx4 %1, %5, off sc0\n\t"                    \
                 "global_load_dwordx4 %2, %6, off sc0\n\t"                    \
                 "global_load_dwordx4 %3, %7, off sc0"                        \
                 : "=&v"(s0v), "=&v"(s1v), "=&v"(s2v), "=&v"(s3v)             \
                 : "v"(p_), "v"(p_ + 4), "v"(p_ + 32), "v"(p_ + 36));         \
  } while (0)

// Wait until tile's loads returned. N = count of YOUNGER LOADS only
// (loads retire in order among themselves; interleaved stores only make the
// wait stricter -> safe under out-of-order store retirement). The "+v" ties
// make every later use of the slot data-depend on this wait.
#define WAITC(Nstr, s0v, s1v, s2v, s3v)                                       \
  asm volatile("s_waitcnt vmcnt(" Nstr ")"                                    \
               : "+v"(s0v), "+v"(s1v), "+v"(s2v), "+v"(s3v)::"memory")

__global__ __launch_bounds__(256) void sqdist_kernel(
    const float* __restrict__ X, const float* __restrict__ W,
    float* __restrict__ Out) {
  const int lane = threadIdx.x & 63;
  const int wid  = threadIdx.x >> 6;
  const int q    = lane >> 4;   // quad 0..3
  const int m    = lane & 15;

  // ---- Setup: w fragments (A operand) + redistributed ||w||^2 ----
  bf16x8 aw[4][2];
  float  w2adj[4][4];  // [ut][reg]: ||w_u||^2 for u = 16*ut + q*4 + reg
#pragma unroll
  for (int ut = 0; ut < 4; ++ut) {
    const float4v* wr = (const float4v*)(W + (ut * 16 + m) * 64);
    float4v v0 = wr[q * 2];
    float4v v1 = wr[q * 2 + 1];
    float4v v2 = wr[8 + q * 2];
    float4v v3 = wr[8 + q * 2 + 1];
    aw[ut][0] = cvt2(v0, v1);
    aw[ut][1] = cvt2(v2, v3);
    float s = 0.f;
#pragma unroll
    for (int i = 0; i < 4; ++i)
      s += v0[i] * v0[i] + v1[i] * v1[i] + v2[i] * v2[i] + v3[i] * v3[i];
    s += __shfl_xor(s, 16);
    s += __shfl_xor(s, 32);
#pragma unroll
    for (int r = 0; r < 4; ++r)
      w2adj[ut][r] = __shfl(s, q * 4 + r);
  }

  const int gw = blockIdx.x * 4 + wid;  // wave id 0..4095; 8 tiles/wave

  // Consume one tile held in registers: norm, cvt, 8 MFMAs, plain stores
  // (compiler-visible stores -> auto-waited, endpgm-safe).
  auto consume = [&](float4v x0, float4v x1, float4v x2, float4v x3, int t) {
    float s = 0.f;
#pragma unroll
    for (int i = 0; i < 4; ++i)
      s += x0[i] * x0[i] + x1[i] * x1[i] + x2[i] * x2[i] + x3[i] * x3[i];
    s += __shfl_xor(s, 16);
    s += __shfl_xor(s, 32);      // s = ||x_(t*16+m)||^2 (C-col of lane = m)

    bf16x8 bx0 = cvt2(x0, x1);
    bf16x8 bx1 = cvt2(x2, x3);

    float4v acc[4];
#pragma unroll
    for (int ut = 0; ut < 4; ++ut) {
      float4v z = {0.f, 0.f, 0.f, 0.f};
      acc[ut] = __builtin_amdgcn_mfma_f32_16x16x32_bf16(aw[ut][0], bx0, z, 0, 0, 0);
      acc[ut] = __builtin_amdgcn_mfma_f32_16x16x32_bf16(aw[ut][1], bx1, acc[ut], 0, 0, 0);
    }

    float4v* orow = (float4v*)(Out + (size_t)(t * 16 + m) * 64);
#pragma unroll
    for (int ut = 0; ut < 4; ++ut) {
      float4v o;
#pragma unroll
      for (int r = 0; r < 4; ++r)
        o[r] = fmaf(-2.f, acc[ut][r], s + w2adj[ut][r]);
      orow[ut * 4 + q] = o;   // floats [16*ut + 4*q .. +3] of this row
    }
  };

  // ---- Depth-3 register pipeline over exactly 8 tiles, hand-unrolled ----
  float4v A0, A1, A2, A3, B0, B1, B2, B3, C0, C1, C2, C3;

  ISSUE(A0, A1, A2, A3, gw + 0 * kWaves);
  ISSUE(B0, B1, B2, B3, gw + 1 * kWaves);
  ISSUE(C0, C1, C2, C3, gw + 2 * kWaves);

  WAITC("8", A0, A1, A2, A3);  consume(A0, A1, A2, A3, gw + 0 * kWaves);
  ISSUE(A0, A1, A2, A3, gw + 3 * kWaves);

  WAITC("8", B0, B1, B2, B3);  consume(B0, B1, B2, B3, gw + 1 * kWaves);
  ISSUE(B0, B1, B2, B3, gw + 4 * kWaves);

  WAITC("8", C0, C1, C2, C3);  consume(C0, C1, C2, C3, gw + 2 * kWaves);
  ISSUE(C0, C1, C2, C3, gw + 5 * kWaves);

  WAITC("8", A0, A1, A2, A3);  consume(A0, A1, A2, A3, gw + 3 * kWaves);
  ISSUE(A0, A1, A2, A3, gw + 6 * kWaves);

  WAITC("8", B0, B1, B2, B3);  consume(B0, B1, B2, B3, gw + 4 * kWaves);
  ISSUE(B0, B1, B2, B3, gw + 7 * kWaves);

  WAITC("8", C0, C1, C2, C3);  consume(C0, C1, C2, C3, gw + 5 * kWaves);

  WAITC("4", A0, A1, A2, A3);  consume(A0, A1, A2, A3, gw + 6 * kWaves);

  WAITC("0", B0, B1, B2, B3);  consume(B0, B1, B2, B3, gw + 7 * kWaves);
}

extern "C" void kernel_launch(void* const* d_in, const int* in_sizes, int n_in,
                              void* d_out, int out_size, void* d_ws, size_t ws_size,
                              hipStream_t stream) {
  const float* X = (const float*)d_in[0];
  const float* W = (const float*)d_in[1];
  float* Out = (float*)d_out;
  // 1024 blocks x 256 (4 waves) = 4096 waves; 8 tiles/wave, depth-3 asm
  // register pipeline with sc0 (L1-bypass) loads.
  sqdist_kernel<<<1024, 256, 0, stream>>>(X, W, Out);
}